// Round 9
// baseline (371.860 us; speedup 1.0000x reference)
//
#include <hip/hip_runtime.h>

#define T_    1024
#define H_    1024
#define IDIM  1024
#define E_    16
#define TOPK  4
#define ALPHA 1.702f
#define LIMIT 7.0f

typedef __bf16 bf16;
typedef __bf16 bf16x4 __attribute__((ext_vector_type(4)));
typedef __bf16 bf16x8 __attribute__((ext_vector_type(8)));
typedef float  f32x4  __attribute__((ext_vector_type(4)));

// Raw barrier WITHOUT vmcnt(0) drain: LDS ordering only (proven).
#define BARRIER() do { \
    asm volatile("s_waitcnt lgkmcnt(0)" ::: "memory"); \
    __builtin_amdgcn_s_barrier(); } while (0)

// ---------------------------------------------------------------------------
// Kernel 1: RMSNorm + router logits + softmax/top-4 + routing lists.
// ---------------------------------------------------------------------------
__global__ __launch_bounds__(256) void k_rms_router(
    const float* __restrict__ x, const float* __restrict__ nw,
    const float* __restrict__ rw, const float* __restrict__ rb,
    const float* __restrict__ mw, const int* __restrict__ lidx,
    bf16* __restrict__ tB, float* __restrict__ out,
    int* __restrict__ cnt, int* __restrict__ tok_list,
    float* __restrict__ wgt_list)
{
    const int t = blockIdx.x, tid = threadIdx.x;
    const int lane = tid & 63, wave = tid >> 6;
    __shared__ float tbuf[H_];
    __shared__ float red[4];
    __shared__ float logits[E_];

    float4 xv = ((const float4*)(x + (size_t)t * H_))[tid];
    float4 wv = ((const float4*)nw)[tid];
    float ssq = xv.x*xv.x + xv.y*xv.y + xv.z*xv.z + xv.w*xv.w;
    #pragma unroll
    for (int off = 32; off; off >>= 1) ssq += __shfl_xor(ssq, off);
    if (lane == 0) red[wave] = ssq;
    __syncthreads();
    const float rms = rsqrtf((red[0] + red[1] + red[2] + red[3]) * (1.0f / H_) + 1e-5f);

    float4 tv;
    tv.x = xv.x * rms * wv.x;
    tv.y = xv.y * rms * wv.y;
    tv.z = xv.z * rms * wv.z;
    tv.w = xv.w * rms * wv.w;

    ((float4*)(out + (size_t)t * H_))[tid] = xv;      // residual init
    ((float4*)tbuf)[tid] = tv;
    bf16x4 tb = { (bf16)tv.x, (bf16)tv.y, (bf16)tv.z, (bf16)tv.w };
    *(bf16x4*)(tB + (size_t)t * H_ + tid * 4) = tb;
    __syncthreads();

    #pragma unroll
    for (int ei = 0; ei < 4; ++ei) {
        const int e = wave * 4 + ei;
        const float* wr = rw + (size_t)e * H_;
        float s = 0.f;
        #pragma unroll
        for (int j = 0; j < 16; ++j) {
            const int c = lane + j * 64;
            s += tbuf[c] * wr[c];
        }
        #pragma unroll
        for (int off = 32; off; off >>= 1) s += __shfl_xor(s, off);
        if (lane == 0) logits[e] = s + rb[e];
    }
    __syncthreads();

    if (tid == 0) {
        float g[E_];
        #pragma unroll
        for (int e = 0; e < E_; ++e) g[e] = logits[e];

        const int li = lidx[0];
        float ma = 0.f, lw[E_];
        #pragma unroll
        for (int e = 0; e < E_; ++e) { lw[e] = mw[li * E_ + e]; ma = fmaxf(ma, fabsf(lw[e])); }
        if (ma > 0.f) {
            float mx = -1e30f;
            for (int e = 0; e < E_; ++e) mx = fmaxf(mx, g[e]);
            float se = 0.f;
            for (int e = 0; e < E_; ++e) se += expf(g[e] - mx);
            const float lse = logf(se) + mx;
            float gl[E_], gmx = -1e30f, gmn = 1e30f;
            for (int e = 0; e < E_; ++e) { gl[e] = g[e] - lse; gmx = fmaxf(gmx, gl[e]); gmn = fminf(gmn, gl[e]); }
            for (int e = 0; e < E_; ++e) {
                if (lw[e] > 0.f)      gl[e] = gmx + 0.01f;
                else if (lw[e] < 0.f) gl[e] = gmn - 0.01f;
                g[e] = gl[e];
            }
        }

        float mx = -1e30f;
        #pragma unroll
        for (int e = 0; e < E_; ++e) mx = fmaxf(mx, g[e]);
        float p[E_];
        #pragma unroll
        for (int e = 0; e < E_; ++e) p[e] = expf(g[e] - mx);

        bool used[E_] = {};
        int   idx[TOPK];
        float twv[TOPK];
        float ssum = 0.f;
        for (int k = 0; k < TOPK; ++k) {
            int best = -1; float bv = -1e30f;
            for (int e = 0; e < E_; ++e)
                if (!used[e] && p[e] > bv) { bv = p[e]; best = e; }
            used[best] = true; idx[k] = best; twv[k] = bv; ssum += bv;
        }
        const float inv = 1.f / ssum;
        for (int k = 0; k < TOPK; ++k) {
            const int e = idx[k];
            const int slot = atomicAdd(&cnt[e], 1);
            tok_list[e * T_ + slot] = t;
            wgt_list[e * T_ + slot] = twv[k] * inv;
        }
    }
}

// ---------------------------------------------------------------------------
// Inline routing scan (single-thread, 128-row tiles). {tiln, e, m0, ne, sb}.
// ---------------------------------------------------------------------------
__device__ __forceinline__ void inline_scan(const int* __restrict__ cnt,
                                            int ti, int tid, int* sm)
{
    if (tid == 0) {
        int c0[E_];
        #pragma unroll
        for (int e = 0; e < E_; ++e) c0[e] = cnt[e];
        int s = 0, nt = 0, ee = 0, mm0 = 0, nee = 0, sbb = 0;
        #pragma unroll
        for (int e = 0; e < E_; ++e) {
            const int c = c0[e];
            const int tcnt = (c + 127) >> 7;
            if (ti >= nt && ti < nt + tcnt) {
                ee = e; mm0 = (ti - nt) * 128; nee = c; sbb = s;
            }
            s += c; nt += tcnt;
        }
        sm[0] = nt; sm[1] = ee; sm[2] = mm0; sm[3] = nee; sm[4] = sbb;
    }
    __syncthreads();
}

// ---------------------------------------------------------------------------
// Kernel 2: grouped gate_up GEMM, BM=128 / 8 waves (512 thr), fp32 weights
// direct. DEPTH-2 B prefetch: each B buffer is reloaded immediately after
// its STAGEB frees it (WAR-safe: reads precede load issue in program
// order), giving 2 full phases of latency cover and 8 B-loads in flight
// per thread (vs 4 at depth-1). Barriers pin the schedule. grid: (16, 48).
// ---------------------------------------------------------------------------
__global__ __launch_bounds__(512) void k_gateup9(
    const bf16* __restrict__ tB, const float* __restrict__ w13,
    const float* __restrict__ b13, const int* __restrict__ cnt,
    const int* __restrict__ tok_list, bf16* __restrict__ act)
{
    const int ti = blockIdx.y, bx = blockIdx.x;
    const int tid = threadIdx.x, lane = tid & 63, wave = tid >> 6;
    const int wm = wave >> 2, wn = wave & 3;
    const int q = lane >> 4, r = lane & 15;

    __shared__ __align__(16) bf16 As[16 * 64 * 8];         // 16 KB
    __shared__ __align__(16) bf16 Bs[1032 * 8];            // 16.5 KB (skewed)
    __shared__ int sm[5];

    inline_scan(cnt, ti, tid, sm);
    if (ti >= sm[0]) return;
    const int e = sm[1], m0 = sm[2], ne = sm[3], sb = sm[4];

    // --- A staging: thread -> row m = tid>>2 (0..127), 32B chunk kq = tid&3 ---
    const int m   = tid >> 2, kq = tid & 3;
    const int mf_s = m >> 4, r_s = m & 15;
    const int kc_s = kq >> 1, q_s = (kq & 1) * 2;
    bf16* wr0 = As + ((size_t)((mf_s * 2 + kc_s) * 64 + q_s * 16 + r_s)) * 8;
    bf16* wr1 = wr0 + 16 * 8;
    int srow = m0 + m; srow = srow < ne ? srow : ne - 1;
    const bf16* pA = tB + (size_t)tok_list[e * T_ + srow] * H_ + kq * 16;

    // --- B staging: c4 = tid&31 (col quad), q6 = tid>>5 (k sub-block) ---
    const int c4 = tid & 31, q6 = tid >> 5;
    const int kcs = q6 >> 3, qs = (q6 >> 1) & 3, jh = q6 & 1;
    const int cc = c4 * 4;                       // 0..124 (gate | up halves)
    const int fB = c4 >> 2, r0 = (c4 & 3) * 4;
    const int RB = fB * 2 + kcs;
    bf16* bwr = Bs + ((size_t)(RB * 64 + (RB >> 1) + qs * 16 + r0)) * 8 + jh * 4;
    const int col = (cc < 64) ? (bx * 64 + cc) : (IDIM + bx * 64 + (cc - 64));
    const float* pB = w13 + (size_t)e * H_ * (2 * IDIM)
                          + (size_t)(kcs * 32 + qs * 8 + jh * 4) * (2 * IDIM) + col;

    f32x4 accg[4] = {};
    f32x4 accu[4] = {};
    uint4  a0a, a0b, a1a, a1b;
    f32x4  br0[4], br1[4];

#define LOADA(A0, A1, s) do { const int ss_ = (s) < 16 ? (s) : 15; \
    A0 = *(const uint4*)(pA + ss_ * 64); \
    A1 = *(const uint4*)(pA + ss_ * 64 + 8); } while (0)
#define LOADB(BR, s) do { const int ss_ = (s) < 16 ? (s) : 15; \
    _Pragma("unroll") \
    for (int j2 = 0; j2 < 4; ++j2) \
        BR[j2] = *(const f32x4*)(pB + (size_t)(ss_ * 64 + j2) * (2 * IDIM)); } while (0)
#define STAGEA(A0, A1) do { *(uint4*)wr0 = A0; *(uint4*)wr1 = A1; } while (0)
#define STAGEB(BR) do { \
    _Pragma("unroll") \
    for (int rr = 0; rr < 4; ++rr) { \
        bf16x4 p = { (bf16)BR[0][rr], (bf16)BR[1][rr], \
                     (bf16)BR[2][rr], (bf16)BR[3][rr] }; \
        *(bf16x4*)(bwr + rr * 8) = p; \
    } } while (0)
#define COMPUTE() do { \
    _Pragma("unroll") \
    for (int kc = 0; kc < 2; ++kc) { \
        bf16x8 afr[4]; \
        _Pragma("unroll") \
        for (int mf = 0; mf < 4; ++mf) \
            afr[mf] = *(const bf16x8*)(As + ((size_t)(((wm * 4 + mf) * 2 + kc) * 64 + lane)) * 8); \
        const int Rg = wn * 2 + kc, Ru = (wn + 4) * 2 + kc; \
        bf16x8 bg = *(const bf16x8*)(Bs + ((size_t)(Rg * 64 + (Rg >> 1) + lane)) * 8); \
        bf16x8 bu = *(const bf16x8*)(Bs + ((size_t)(Ru * 64 + (Ru >> 1) + lane)) * 8); \
        _Pragma("unroll") \
        for (int mf = 0; mf < 4; ++mf) { \
            accg[mf] = __builtin_amdgcn_mfma_f32_16x16x32_bf16(afr[mf], bg, accg[mf], 0, 0, 0); \
            accu[mf] = __builtin_amdgcn_mfma_f32_16x16x32_bf16(afr[mf], bu, accu[mf], 0, 0, 0); \
        } \
    } } while (0)

    LOADA(a0a, a0b, 0);
    LOADB(br0, 0);
    LOADB(br1, 1);
    #pragma unroll 1
    for (int kb = 0; kb < 16; kb += 2) {
        BARRIER();
        STAGEA(a0a, a0b);  STAGEB(br0);
        LOADA(a1a, a1b, kb + 1);  LOADB(br0, kb + 2);   // depth-2: reload freed buf
        BARRIER();
        COMPUTE();

        BARRIER();
        STAGEA(a1a, a1b);  STAGEB(br1);
        LOADA(a0a, a0b, kb + 2);  LOADB(br1, kb + 3);
        BARRIER();
        COMPUTE();
    }
#undef LOADA
#undef LOADB
#undef STAGEA
#undef STAGEB
#undef COMPUTE

    // --- epilogue ---
    const int nb_g = bx * 4 + wn;
    const int cg = nb_g * 16 + r;
    const float bgv = b13[e * 2 * IDIM + cg];
    const float buv = b13[e * 2 * IDIM + IDIM + cg];
    #pragma unroll
    for (int mf = 0; mf < 4; ++mf) {
        #pragma unroll
        for (int rg = 0; rg < 4; ++rg) {
            const int row = wm * 64 + mf * 16 + q * 4 + rg;
            if (m0 + row < ne) {
                const float hg = accg[mf][rg] + bgv;
                const float hu = accu[mf][rg] + buv;
                const float gt = fminf(hg, LIMIT);
                const float up = fminf(fmaxf(hu, -LIMIT), LIMIT);
                const float av = (up + 1.0f) * gt / (1.0f + expf(-ALPHA * gt));
                act[(size_t)(sb + m0 + row) * IDIM + cg] = (bf16)av;
            }
        }
    }
}

// ---------------------------------------------------------------------------
// Kernel 3: grouped down GEMM + weighted atomic combine, BM=128 / 8 waves,
// depth-2 B prefetch. grid: (8, 48).
// ---------------------------------------------------------------------------
__global__ __launch_bounds__(512) void k_down9(
    const bf16* __restrict__ act, const float* __restrict__ w2,
    const float* __restrict__ b2, const int* __restrict__ cnt,
    const int* __restrict__ tok_list, const float* __restrict__ wgt_list,
    float* __restrict__ out)
{
    const int ti = blockIdx.y, bx = blockIdx.x;
    const int tid = threadIdx.x, lane = tid & 63, wave = tid >> 6;
    const int wm = wave >> 2, wn = wave & 3;
    const int q = lane >> 4, r = lane & 15;

    __shared__ __align__(16) bf16 As[16 * 64 * 8];
    __shared__ __align__(16) bf16 Bs[1032 * 8];
    __shared__ int sm[5];

    inline_scan(cnt, ti, tid, sm);
    if (ti >= sm[0]) return;
    const int e = sm[1], m0 = sm[2], ne = sm[3], sb = sm[4];

    const int m   = tid >> 2, kq = tid & 3;
    const int mf_s = m >> 4, r_s = m & 15;
    const int kc_s = kq >> 1, q_s = (kq & 1) * 2;
    bf16* wr0 = As + ((size_t)((mf_s * 2 + kc_s) * 64 + q_s * 16 + r_s)) * 8;
    bf16* wr1 = wr0 + 16 * 8;
    int srow = m0 + m; srow = srow < ne ? srow : ne - 1;
    const bf16* pA = act + (size_t)(sb + srow) * IDIM + kq * 16;

    const int c4 = tid & 31, q6 = tid >> 5;
    const int kcs = q6 >> 3, qs = (q6 >> 1) & 3, jh = q6 & 1;
    const int cc = c4 * 4;
    const int fB = c4 >> 2, r0 = (c4 & 3) * 4;
    const int RB = fB * 2 + kcs;
    bf16* bwr = Bs + ((size_t)(RB * 64 + (RB >> 1) + qs * 16 + r0)) * 8 + jh * 4;
    const float* pB = w2 + (size_t)e * IDIM * H_
                         + (size_t)(kcs * 32 + qs * 8 + jh * 4) * H_ + bx * 128 + cc;

    f32x4 acc[4][2] = {};
    uint4  a0a, a0b, a1a, a1b;
    f32x4  br0[4], br1[4];

#define LOADA(A0, A1, s) do { const int ss_ = (s) < 16 ? (s) : 15; \
    A0 = *(const uint4*)(pA + ss_ * 64); \
    A1 = *(const uint4*)(pA + ss_ * 64 + 8); } while (0)
#define LOADB(BR, s) do { const int ss_ = (s) < 16 ? (s) : 15; \
    _Pragma("unroll") \
    for (int j2 = 0; j2 < 4; ++j2) \
        BR[j2] = *(const f32x4*)(pB + (size_t)(ss_ * 64 + j2) * H_); } while (0)
#define STAGEA(A0, A1) do { *(uint4*)wr0 = A0; *(uint4*)wr1 = A1; } while (0)
#define STAGEB(BR) do { \
    _Pragma("unroll") \
    for (int rr = 0; rr < 4; ++rr) { \
        bf16x4 p = { (bf16)BR[0][rr], (bf16)BR[1][rr], \
                     (bf16)BR[2][rr], (bf16)BR[3][rr] }; \
        *(bf16x4*)(bwr + rr * 8) = p; \
    } } while (0)
#define COMPUTE() do { \
    _Pragma("unroll") \
    for (int kc = 0; kc < 2; ++kc) { \
        bf16x8 afr[4]; \
        _Pragma("unroll") \
        for (int mf = 0; mf < 4; ++mf) \
            afr[mf] = *(const bf16x8*)(As + ((size_t)(((wm * 4 + mf) * 2 + kc) * 64 + lane)) * 8); \
        const int R0 = (wn * 2) * 2 + kc, R1 = (wn * 2 + 1) * 2 + kc; \
        bf16x8 b0 = *(const bf16x8*)(Bs + ((size_t)(R0 * 64 + (R0 >> 1) + lane)) * 8); \
        bf16x8 b1 = *(const bf16x8*)(Bs + ((size_t)(R1 * 64 + (R1 >> 1) + lane)) * 8); \
        _Pragma("unroll") \
        for (int mf = 0; mf < 4; ++mf) { \
            acc[mf][0] = __builtin_amdgcn_mfma_f32_16x16x32_bf16(afr[mf], b0, acc[mf][0], 0, 0, 0); \
            acc[mf][1] = __builtin_amdgcn_mfma_f32_16x16x32_bf16(afr[mf], b1, acc[mf][1], 0, 0, 0); \
        } \
    } } while (0)

    LOADA(a0a, a0b, 0);
    LOADB(br0, 0);
    LOADB(br1, 1);
    #pragma unroll 1
    for (int kb = 0; kb < 16; kb += 2) {
        BARRIER();
        STAGEA(a0a, a0b);  STAGEB(br0);
        LOADA(a1a, a1b, kb + 1);  LOADB(br0, kb + 2);   // depth-2
        BARRIER();
        COMPUTE();

        BARRIER();
        STAGEA(a1a, a1b);  STAGEB(br1);
        LOADA(a0a, a0b, kb + 2);  LOADB(br1, kb + 3);
        BARRIER();
        COMPUTE();
    }
#undef LOADA
#undef LOADB
#undef STAGEA
#undef STAGEB
#undef COMPUTE

    const int nb0 = bx * 8 + wn * 2;
    #pragma unroll
    for (int nf = 0; nf < 2; ++nf) {
        const int ch = (nb0 + nf) * 16 + r;
        const float bb = b2[e * H_ + ch];
        #pragma unroll
        for (int mf = 0; mf < 4; ++mf) {
            #pragma unroll
            for (int rg = 0; rg < 4; ++rg) {
                const int row = wm * 64 + mf * 16 + q * 4 + rg;
                const int s = m0 + row;
                if (s < ne) {
                    const int   tok = tok_list[e * T_ + s];
                    const float w   = wgt_list[e * T_ + s];
                    atomicAdd(&out[(size_t)tok * H_ + ch], w * (acc[mf][nf][rg] + bb));
                }
            }
        }
    }
}

// ---------------------------------------------------------------------------
extern "C" void kernel_launch(void* const* d_in, const int* in_sizes, int n_in,
                              void* d_out, int out_size, void* d_ws, size_t ws_size,
                              hipStream_t stream)
{
    const float* x        = (const float*)d_in[0];
    const float* norm_w   = (const float*)d_in[1];
    const float* router_w = (const float*)d_in[2];
    const float* router_b = (const float*)d_in[3];
    const float* w13      = (const float*)d_in[4];
    const float* b13      = (const float*)d_in[5];
    const float* w2       = (const float*)d_in[6];
    const float* b2       = (const float*)d_in[7];
    const float* manual_w = (const float*)d_in[8];
    const int*   layer_i  = (const int*)d_in[9];
    float* out = (float*)d_out;

    char* ws = (char*)d_ws;
    bf16*  tB   = (bf16*)ws;                              // 2 MB @ 0
    bf16*  act  = (bf16*)(ws + (2ull << 20));             // 8 MB @ 2M
    char*  meta = ws + (10ull << 20);
    int*   cnt      = (int*)meta;                         // 16 ints
    int*   tok_list = (int*)(meta + (16ull << 10));       // 64 KB
    float* wgt_list = (float*)(meta + (16ull << 10) + (64ull << 10)); // 64 KB

    hipMemsetAsync(cnt, 0, E_ * sizeof(int), stream);

    k_rms_router<<<T_, 256, 0, stream>>>(x, norm_w, router_w, router_b,
                                         manual_w, layer_i, tB, out,
                                         cnt, tok_list, wgt_list);

    dim3 gg(16, 48);
    k_gateup9<<<gg, 512, 0, stream>>>(tB, w13, b13, cnt, tok_list, act);
    dim3 gd(8, 48);
    k_down9<<<gd, 512, 0, stream>>>(act, w2, b2, cnt, tok_list, wgt_list, out);
}